// Round 1
// baseline (1832.457 us; speedup 1.0000x reference)
//
#include <hip/hip_runtime.h>
#include <math.h>

#define B_    8192
#define K_    64
#define C_    64
#define FEAT_ 172
#define TDIM_ 100
#define IND_  272      // FEAT_+TDIM_
#define TOKH_ 32
#define CHH_  256
#define G_    100
#define L_    2
#define CAT_  236      // C_+FEAT_

__device__ __forceinline__ float gelu_exact(float x) {
    return 0.5f * x * (1.0f + erff(x * 0.70710678118654752f));
}

// ---------------------------------------------------------------------------
// Kernel 1: gather edge feats + time encoding + projection (272 -> 64)
// Output x stored as [b][c][k] (c-major) for the mixer.
// lane = k (64 rows), wave w owns output channels c = w*16 .. w*16+15.
// Weights read with wave-uniform indices -> scalar loads (s_load, free pipe).
// Staged in two i-chunks of 136 to keep LDS at 35.4 KB (4 blocks/CU).
// ---------------------------------------------------------------------------
__global__ __launch_bounds__(256)
void proj_kernel(const float* __restrict__ edge_table,
                 const float* __restrict__ time_w,
                 const float* __restrict__ proj_W,
                 const float* __restrict__ proj_b,
                 const int*   __restrict__ nbr_node_ids,
                 const int*   __restrict__ nbr_edge_ids,
                 const float* __restrict__ node_times,
                 const float* __restrict__ nbr_times,
                 float* __restrict__ x_out) {
    __shared__ float inT[136 * 65];   // [i_local][k], stride 65 (conflict-free)

    const int b    = blockIdx.x;
    const int t    = threadIdx.x;
    const int k    = t & 63;
    const int w    = __builtin_amdgcn_readfirstlane(t >> 6);
    const int cbase = w * 16;

    const size_t eid = (size_t)nbr_edge_ids[b * K_ + k];
    const float* erow = edge_table + eid * FEAT_;
    const int   nzero = (nbr_node_ids[b * K_ + k] == 0);
    const float dt    = node_times[b] - nbr_times[b * K_ + k];

    float acc[16];
#pragma unroll
    for (int j = 0; j < 16; ++j) acc[j] = proj_b[cbase + j];

    // ---- pass A: edge feature f4-chunks m = 0..33  (i = 0..135) ----
    for (int m = w; m < 34; m += 4) {
        float4 v = *(const float4*)(erow + 4 * m);
        const int i0 = 4 * m;
        inT[(i0 + 0) * 65 + k] = v.x;
        inT[(i0 + 1) * 65 + k] = v.y;
        inT[(i0 + 2) * 65 + k] = v.z;
        inT[(i0 + 3) * 65 + k] = v.w;
    }
    __syncthreads();
#pragma unroll 4
    for (int i = 0; i < 136; ++i) {
        const float v = inT[i * 65 + k];
        const float* wr = proj_W + i * C_ + cbase;   // wave-uniform -> s_load
#pragma unroll
        for (int j = 0; j < 16; ++j) acc[j] += v * wr[j];
    }
    __syncthreads();

    // ---- pass B: edge chunks m = 34..42 (i = 136..171) + time feats ----
    for (int m = 34 + w; m < 43; m += 4) {
        float4 v = *(const float4*)(erow + 4 * m);
        const int i0 = 4 * m - 136;
        inT[(i0 + 0) * 65 + k] = v.x;
        inT[(i0 + 1) * 65 + k] = v.y;
        inT[(i0 + 2) * 65 + k] = v.z;
        inT[(i0 + 3) * 65 + k] = v.w;
    }
    for (int d = w; d < TDIM_; d += 4) {
        float v = nzero ? 0.0f : cosf(dt * time_w[d]);
        inT[(36 + d) * 65 + k] = v;    // i = 172+d, local = i-136
    }
    __syncthreads();
#pragma unroll 4
    for (int i = 0; i < 136; ++i) {
        const float v = inT[i * 65 + k];
        const float* wr = proj_W + (136 + i) * C_ + cbase;
#pragma unroll
        for (int j = 0; j < 16; ++j) acc[j] += v * wr[j];
    }

    float* xo = x_out + (size_t)b * (C_ * K_);
#pragma unroll
    for (int j = 0; j < 16; ++j) xo[(cbase + j) * K_ + k] = acc[j];
}

// ---------------------------------------------------------------------------
// Kernel 2: fused 2-layer MLP-Mixer per batch element; x lives in LDS.
// xT[c][k] stride 65. Token path: lane=c; channel path: lane=k.
// All weight reads are wave-uniform -> scalar pipe.
// ---------------------------------------------------------------------------
__global__ __launch_bounds__(256)
void mixer_kernel(const float* __restrict__ x_buf,   // [b][c][k]
                  const float* __restrict__ tok_ln_s, const float* __restrict__ tok_ln_b,
                  const float* __restrict__ tok_W1,   const float* __restrict__ tok_b1,
                  const float* __restrict__ tok_W2,   const float* __restrict__ tok_b2,
                  const float* __restrict__ ch_ln_s,  const float* __restrict__ ch_ln_b,
                  const float* __restrict__ ch_W1,    const float* __restrict__ ch_b1,
                  const float* __restrict__ ch_W2,    const float* __restrict__ ch_b2,
                  float* __restrict__ agg_out) {      // [b][c]
    __shared__ float xT[C_ * 65];
    __shared__ float xh[C_ * 65];
    __shared__ float hbuf[2112];      // token: [c][j] str33 ; channel: [jj][k] str65
    __shared__ float redA[4 * 64], redB[4 * 64];
    __shared__ float stm[64], str_[64];

    const int b    = blockIdx.x;
    const int t    = threadIdx.x;
    const int lane = t & 63;
    const int w    = __builtin_amdgcn_readfirstlane(t >> 6);

    // load x tile (coalesced f4)
    const float* xg = x_buf + (size_t)b * 4096;
    for (int m = t; m < 1024; m += 256) {
        float4 v = *(const float4*)(xg + 4 * m);
        const int g = 4 * m, c = g >> 6, kk = g & 63;
        xT[c * 65 + kk + 0] = v.x;
        xT[c * 65 + kk + 1] = v.y;
        xT[c * 65 + kk + 2] = v.z;
        xT[c * 65 + kk + 3] = v.w;
    }
    __syncthreads();

    for (int l = 0; l < L_; ++l) {
        // ================= token mixing =================
        {   // stats per channel c over k
            const int c = lane;
            float s = 0.f, ss = 0.f;
            for (int kk = w * 16; kk < w * 16 + 16; ++kk) {
                const float v = xT[c * 65 + kk];
                s += v; ss += v * v;
            }
            redA[w * 64 + c] = s; redB[w * 64 + c] = ss;
        }
        __syncthreads();
        if (t < 64) {
            const float s  = redA[t] + redA[64 + t] + redA[128 + t] + redA[192 + t];
            const float ss = redB[t] + redB[64 + t] + redB[128 + t] + redB[192 + t];
            const float m  = s * (1.0f / 64.0f);
            const float var = ss * (1.0f / 64.0f) - m * m;
            stm[t]  = m;
            str_[t] = rsqrtf(var + 1e-5f);
        }
        __syncthreads();
        {   // xh[c][k] = (x-m)*r * tls[k] + tlb[k]
            const int c = lane;
            const float m = stm[c], r = str_[c];
            const float* tls = tok_ln_s + l * K_;
            const float* tlb = tok_ln_b + l * K_;
            for (int kk = w * 16; kk < w * 16 + 16; ++kk)
                xh[c * 65 + kk] = (xT[c * 65 + kk] - m) * r * tls[kk] + tlb[kk];
        }
        __syncthreads();
        {   // H1[c][j] = gelu(sum_k xh[c][k]*W1[k][j] + b1[j]); wave w: j = w*8..+7
            const int c = lane;
            const float* W1 = tok_W1 + l * K_ * TOKH_;
            float h[8];
#pragma unroll
            for (int j = 0; j < 8; ++j) h[j] = tok_b1[l * TOKH_ + w * 8 + j];
#pragma unroll 4
            for (int kk = 0; kk < K_; ++kk) {
                const float v = xh[c * 65 + kk];
                const float* wr = W1 + kk * TOKH_ + w * 8;
#pragma unroll
                for (int j = 0; j < 8; ++j) h[j] += v * wr[j];
            }
#pragma unroll
            for (int j = 0; j < 8; ++j) hbuf[c * 33 + w * 8 + j] = gelu_exact(h[j]);
        }
        __syncthreads();
        {   // x[c][k] += sum_j H1[c][j]*W2[j][k] + b2[k]; wave w: k = w*16..+15
            const int c = lane;
            const float* W2 = tok_W2 + l * TOKH_ * K_;
            float acc[16];
#pragma unroll
            for (int m2 = 0; m2 < 16; ++m2) acc[m2] = tok_b2[l * K_ + w * 16 + m2];
#pragma unroll 4
            for (int j = 0; j < TOKH_; ++j) {
                const float v = hbuf[c * 33 + j];
                const float* wr = W2 + j * K_ + w * 16;
#pragma unroll
                for (int m2 = 0; m2 < 16; ++m2) acc[m2] += v * wr[m2];
            }
#pragma unroll
            for (int m2 = 0; m2 < 16; ++m2) xT[c * 65 + w * 16 + m2] += acc[m2];
        }
        __syncthreads();

        // ================= channel mixing =================
        {   // stats per row k over c
            const int kk = lane;
            float s = 0.f, ss = 0.f;
            for (int c = w * 16; c < w * 16 + 16; ++c) {
                const float v = xT[c * 65 + kk];
                s += v; ss += v * v;
            }
            redA[w * 64 + kk] = s; redB[w * 64 + kk] = ss;
        }
        __syncthreads();
        if (t < 64) {
            const float s  = redA[t] + redA[64 + t] + redA[128 + t] + redA[192 + t];
            const float ss = redB[t] + redB[64 + t] + redB[128 + t] + redB[192 + t];
            const float m  = s * (1.0f / 64.0f);
            const float var = ss * (1.0f / 64.0f) - m * m;
            stm[t]  = m;
            str_[t] = rsqrtf(var + 1e-5f);
        }
        __syncthreads();
        {   // xh[c][k] = (x[c][k]-m[k])*r[k] * cls[c] + clb[c]
            const int kk = lane;
            const float m = stm[kk], r = str_[kk];
            const float* cls = ch_ln_s + l * C_;
            const float* clb = ch_ln_b + l * C_;
            for (int c = w * 16; c < w * 16 + 16; ++c)
                xh[c * 65 + kk] = (xT[c * 65 + kk] - m) * r * cls[c] + clb[c];
        }
        __syncthreads();
        {   // channel MLP, j-tiles of 32; lane = k; wave w owns c_out = w*16..+15
            const int kk = lane;
            const float* W1 = ch_W1 + l * C_ * CHH_;
            const float* W2 = ch_W2 + l * CHH_ * C_;
            float delta[16];
#pragma unroll
            for (int m2 = 0; m2 < 16; ++m2) delta[m2] = ch_b2[l * C_ + w * 16 + m2];
            for (int blk = 0; blk < CHH_ / 32; ++blk) {
                const int jb = blk * 32 + w * 8;
                float h[8];
#pragma unroll
                for (int j = 0; j < 8; ++j) h[j] = ch_b1[l * CHH_ + jb + j];
#pragma unroll 4
                for (int c = 0; c < C_; ++c) {
                    const float v = xh[c * 65 + kk];
                    const float* wr = W1 + c * CHH_ + jb;
#pragma unroll
                    for (int j = 0; j < 8; ++j) h[j] += v * wr[j];
                }
#pragma unroll
                for (int j = 0; j < 8; ++j) hbuf[(w * 8 + j) * 65 + kk] = gelu_exact(h[j]);
                __syncthreads();
#pragma unroll 4
                for (int jj = 0; jj < 32; ++jj) {
                    const float v = hbuf[jj * 65 + kk];
                    const float* wr = W2 + (blk * 32 + jj) * C_ + w * 16;
#pragma unroll
                    for (int m2 = 0; m2 < 16; ++m2) delta[m2] += v * wr[m2];
                }
                __syncthreads();
            }
#pragma unroll
            for (int m2 = 0; m2 < 16; ++m2) xT[(w * 16 + m2) * 65 + kk] += delta[m2];
        }
        __syncthreads();
    }

    // agg[b][c] = mean over k
    if (t < 64) {
        float s = 0.f;
        for (int kk = 0; kk < K_; ++kk) s += xT[t * 65 + kk];
        agg_out[(size_t)b * C_ + t] = s * (1.0f / 64.0f);
    }
}

// ---------------------------------------------------------------------------
// Kernel 3: gap aggregation (softmax over valid == uniform 1/nvalid) + output GEMV
// ---------------------------------------------------------------------------
__global__ __launch_bounds__(192)
void out_kernel(const float* __restrict__ node_table,
                const float* __restrict__ agg,
                const float* __restrict__ out_W,
                const float* __restrict__ out_b,
                const int*   __restrict__ node_ids,
                const int*   __restrict__ gap_ids,
                float* __restrict__ out) {
    __shared__ float inb[CAT_];
    const int b = blockIdx.x;
    const int t = threadIdx.x;

    if (t < 64) inb[t] = agg[(size_t)b * C_ + t];

    if (t < FEAT_) {
        const int* gid = gap_ids + (size_t)b * G_;
        float acc = 0.f;
        int nv = 0;
#pragma unroll 4
        for (int g = 0; g < G_; ++g) {
            const int id = gid[g];      // uniform across lanes -> broadcast
            if (id > 0) { ++nv; acc += node_table[(size_t)id * FEAT_ + t]; }
        }
        const int nvs = (nv > 0) ? nv : 1;
        const float scale = 1.0f / (float)(G_ * nvs);
        const int nid = node_ids[b];
        inb[64 + t] = acc * scale + node_table[(size_t)nid * FEAT_ + t];
    }
    __syncthreads();

    if (t < FEAT_) {
        float o = out_b[t];
#pragma unroll 4
        for (int i = 0; i < CAT_; ++i) o += inb[i] * out_W[i * FEAT_ + t];
        out[(size_t)b * FEAT_ + t] = o;
    }
}

// ---------------------------------------------------------------------------
extern "C" void kernel_launch(void* const* d_in, const int* in_sizes, int n_in,
                              void* d_out, int out_size, void* d_ws, size_t ws_size,
                              hipStream_t stream) {
    const float* node_table = (const float*)d_in[0];
    const float* edge_table = (const float*)d_in[1];
    const float* time_w     = (const float*)d_in[2];
    const float* proj_W     = (const float*)d_in[3];
    const float* proj_b     = (const float*)d_in[4];
    const float* tok_ln_s   = (const float*)d_in[5];
    const float* tok_ln_b   = (const float*)d_in[6];
    const float* tok_W1     = (const float*)d_in[7];
    const float* tok_b1     = (const float*)d_in[8];
    const float* tok_W2     = (const float*)d_in[9];
    const float* tok_b2     = (const float*)d_in[10];
    const float* ch_ln_s    = (const float*)d_in[11];
    const float* ch_ln_b    = (const float*)d_in[12];
    const float* ch_W1      = (const float*)d_in[13];
    const float* ch_b1      = (const float*)d_in[14];
    const float* ch_W2      = (const float*)d_in[15];
    const float* ch_b2      = (const float*)d_in[16];
    const float* out_W      = (const float*)d_in[17];
    const float* out_b      = (const float*)d_in[18];
    const int*   node_ids   = (const int*)d_in[19];
    const int*   nbr_nids   = (const int*)d_in[20];
    const int*   nbr_eids   = (const int*)d_in[21];
    const int*   gap_ids    = (const int*)d_in[22];
    const float* node_times = (const float*)d_in[23];
    const float* nbr_times  = (const float*)d_in[24];

    float* x_buf   = (float*)d_ws;                       // B*C*K f32 = 128 MB
    float* agg_buf = x_buf + (size_t)B_ * C_ * K_;       // B*C f32  = 2 MB
    float* outp    = (float*)d_out;

    proj_kernel<<<B_, 256, 0, stream>>>(edge_table, time_w, proj_W, proj_b,
                                        nbr_nids, nbr_eids, node_times, nbr_times,
                                        x_buf);
    mixer_kernel<<<B_, 256, 0, stream>>>(x_buf,
                                         tok_ln_s, tok_ln_b, tok_W1, tok_b1, tok_W2, tok_b2,
                                         ch_ln_s, ch_ln_b, ch_W1, ch_b1, ch_W2, ch_b2,
                                         agg_buf);
    out_kernel<<<B_, 192, 0, stream>>>(node_table, agg_buf, out_W, out_b,
                                       node_ids, gap_ids, outp);
}

// Round 2
// 1112.552 us; speedup vs baseline: 1.6471x; 1.6471x over previous
//
#include <hip/hip_runtime.h>
#include <math.h>

#define B_    8192
#define K_    64
#define C_    64
#define FEAT_ 172
#define TDIM_ 100
#define TOKH_ 32
#define CHH_  256
#define G_    100
#define L_    2
#define CAT_  236      // C_+FEAT_

typedef _Float16 f16x8 __attribute__((ext_vector_type(8)));
typedef float    f32x4 __attribute__((ext_vector_type(4)));

__device__ __forceinline__ float gelu_f(float x) {
    // exact-form GELU via Abramowitz-Stegun 7.1.26 erf (|err| < 1.5e-7)
    const float z  = x * 0.70710678118654752f;
    const float az = fabsf(z);
    const float t  = 1.0f / (1.0f + 0.3275911f * az);
    const float poly = t * (0.254829592f + t * (-0.284496736f + t * (1.421413741f
                     + t * (-1.453152027f + t * 1.061405429f))));
    const float e  = __expf(-az * az);
    float erfv = 1.0f - poly * e;
    erfv = copysignf(erfv, z);
    return 0.5f * x * (1.0f + erfv);
}

// ---------------------------------------------------------------------------
// Prepack: transpose weights to f16 [N][K] so MFMA B-fragments are contiguous
// 16B loads.
// ---------------------------------------------------------------------------
__global__ __launch_bounds__(256)
void prepack_kernel(const float* __restrict__ tW1, const float* __restrict__ tW2,
                    const float* __restrict__ cW1, const float* __restrict__ cW2,
                    _Float16* __restrict__ pT1, _Float16* __restrict__ pT2,
                    _Float16* __restrict__ pC1, _Float16* __restrict__ pC2) {
    const int stride = gridDim.x * blockDim.x;
    const int t0 = blockIdx.x * blockDim.x + threadIdx.x;
    // pT1[l][j][k] = tW1[l][k][j]   tW1: (2,64,32)
    for (int i = t0; i < 2 * 32 * 64; i += stride) {
        const int l = i / 2048, rem = i % 2048, j = rem / 64, k = rem % 64;
        pT1[i] = (_Float16)tW1[l * 2048 + k * 32 + j];
    }
    // pT2[l][k][j] = tW2[l][j][k]   tW2: (2,32,64)
    for (int i = t0; i < 2 * 64 * 32; i += stride) {
        const int l = i / 2048, rem = i % 2048, k = rem / 32, j = rem % 32;
        pT2[i] = (_Float16)tW2[l * 2048 + j * 64 + k];
    }
    // pC1[l][n][c] = cW1[l][c][n]   cW1: (2,64,256)
    for (int i = t0; i < 2 * 256 * 64; i += stride) {
        const int l = i / 16384, rem = i % 16384, n = rem / 64, c = rem % 64;
        pC1[i] = (_Float16)cW1[l * 16384 + c * 256 + n];
    }
    // pC2[l][c][n] = cW2[l][n][c]   cW2: (2,256,64)
    for (int i = t0; i < 2 * 64 * 256; i += stride) {
        const int l = i / 16384, rem = i % 16384, c = rem / 256, n = rem % 256;
        pC2[i] = (_Float16)cW2[l * 16384 + n * 64 + c];
    }
}

// ---------------------------------------------------------------------------
// Kernel 1: gather edge feats + time encoding + projection (272 -> 64)
// Output x stored as [b][k][c] (k-major) for the MFMA mixer.
// ---------------------------------------------------------------------------
__global__ __launch_bounds__(256)
void proj_kernel(const float* __restrict__ edge_table,
                 const float* __restrict__ time_w,
                 const float* __restrict__ proj_W,
                 const float* __restrict__ proj_b,
                 const int*   __restrict__ nbr_node_ids,
                 const int*   __restrict__ nbr_edge_ids,
                 const float* __restrict__ node_times,
                 const float* __restrict__ nbr_times,
                 float* __restrict__ x_out) {
    __shared__ float inT[136 * 65];   // [i_local][k], stride 65

    const int b    = blockIdx.x;
    const int t    = threadIdx.x;
    const int k    = t & 63;
    const int w    = __builtin_amdgcn_readfirstlane(t >> 6);
    const int cbase = w * 16;

    const size_t eid = (size_t)nbr_edge_ids[b * K_ + k];
    const float* erow = edge_table + eid * FEAT_;
    const int   nzero = (nbr_node_ids[b * K_ + k] == 0);
    const float dt    = node_times[b] - nbr_times[b * K_ + k];

    float acc[16];
#pragma unroll
    for (int j = 0; j < 16; ++j) acc[j] = proj_b[cbase + j];

    for (int m = w; m < 34; m += 4) {
        float4 v = *(const float4*)(erow + 4 * m);
        const int i0 = 4 * m;
        inT[(i0 + 0) * 65 + k] = v.x;
        inT[(i0 + 1) * 65 + k] = v.y;
        inT[(i0 + 2) * 65 + k] = v.z;
        inT[(i0 + 3) * 65 + k] = v.w;
    }
    __syncthreads();
#pragma unroll 4
    for (int i = 0; i < 136; ++i) {
        const float v = inT[i * 65 + k];
        const float* wr = proj_W + i * C_ + cbase;
#pragma unroll
        for (int j = 0; j < 16; ++j) acc[j] += v * wr[j];
    }
    __syncthreads();

    for (int m = 34 + w; m < 43; m += 4) {
        float4 v = *(const float4*)(erow + 4 * m);
        const int i0 = 4 * m - 136;
        inT[(i0 + 0) * 65 + k] = v.x;
        inT[(i0 + 1) * 65 + k] = v.y;
        inT[(i0 + 2) * 65 + k] = v.z;
        inT[(i0 + 3) * 65 + k] = v.w;
    }
    for (int d = w; d < TDIM_; d += 4) {
        float v = nzero ? 0.0f : cosf(dt * time_w[d]);
        inT[(36 + d) * 65 + k] = v;
    }
    __syncthreads();
#pragma unroll 4
    for (int i = 0; i < 136; ++i) {
        const float v = inT[i * 65 + k];
        const float* wr = proj_W + (136 + i) * C_ + cbase;
#pragma unroll
        for (int j = 0; j < 16; ++j) acc[j] += v * wr[j];
    }

    float* xo = x_out + (size_t)b * (C_ * K_);
#pragma unroll
    for (int j = 0; j < 16; ++j) xo[k * C_ + cbase + j] = acc[j];
}

// ---------------------------------------------------------------------------
// Kernel 2: fused 2-layer MLP-Mixer, MFMA (f16 in, f32 acc).
// One b per block, 4 waves. Wave w owns rows [16w,16w+16) of EVERY
// intermediate -> all inter-GEMM LDS traffic is wave-local -> 4 barriers/layer.
// x state stays f32 in LDS (stride 68); f16 A-operand buffer stride 72 and
// f32 H buffer strides 68/36 give bank-balanced ds_read_b128.
// MFMA frag map (measured, guide §3): A: lane l -> row l&15, k=8*(l>>4)+i;
// B^T[N][K] same pattern; D: col=l&15, row=4*(l>>4)+j.
// ---------------------------------------------------------------------------
__global__ __launch_bounds__(256)
void mixer_mfma(const float* __restrict__ x_buf,
                const float* __restrict__ tok_ln_s, const float* __restrict__ tok_ln_b,
                const float* __restrict__ tok_b1,  const float* __restrict__ tok_b2,
                const float* __restrict__ ch_ln_s, const float* __restrict__ ch_ln_b,
                const float* __restrict__ ch_b1,   const float* __restrict__ ch_b2,
                const _Float16* __restrict__ pT1, const _Float16* __restrict__ pT2,
                const _Float16* __restrict__ pC1, const _Float16* __restrict__ pC2,
                float* __restrict__ agg_out) {
    __shared__ __attribute__((aligned(16))) float    xf[64 * 68];
    __shared__ __attribute__((aligned(16))) _Float16 xh[64 * 72];
    __shared__ __attribute__((aligned(16))) float    Hq[64 * 68];

    const int b    = blockIdx.x;
    const int t    = threadIdx.x;
    const int lane = t & 63;
    const int w    = t >> 6;
    const int r    = lane & 15;
    const int g    = lane >> 4;

    // ---- load x[k][c] ----
    const float* xg = x_buf + (size_t)b * 4096;
    for (int m = t; m < 1024; m += 256) {
        const float4 v = *(const float4*)(xg + 4 * m);
        const int e = 4 * m, k = e >> 6, c = e & 63;
        float* p = &xf[k * 68 + c];
        p[0] = v.x; p[1] = v.y; p[2] = v.z; p[3] = v.w;
    }
    __syncthreads();

    for (int l = 0; l < L_; ++l) {
        // ======== token mixing: LN over k per c ========
        {
            const int c0 = 16 * w + r;
            float xv[16];
            float s = 0.f, ss = 0.f;
#pragma unroll
            for (int u = 0; u < 16; ++u) {
                const float v = xf[(16 * g + u) * 68 + c0];
                xv[u] = v; s += v; ss += v * v;
            }
            s += __shfl_xor(s, 16); ss += __shfl_xor(ss, 16);
            s += __shfl_xor(s, 32); ss += __shfl_xor(ss, 32);
            const float mean = s * (1.f / 64.f);
            const float rstd = rsqrtf(ss * (1.f / 64.f) - mean * mean + 1e-5f);
            const float* tls = tok_ln_s + l * 64 + 16 * g;
            const float* tlb = tok_ln_b + l * 64 + 16 * g;
            f16x8 h0, h1;
#pragma unroll
            for (int u = 0; u < 8; ++u)
                h0[u] = (_Float16)((xv[u] - mean) * rstd * tls[u] + tlb[u]);
#pragma unroll
            for (int u = 0; u < 8; ++u)
                h1[u] = (_Float16)((xv[8 + u] - mean) * rstd * tls[8 + u] + tlb[8 + u]);
            *(f16x8*)&xh[c0 * 72 + 16 * g]     = h0;   // xhT[c][k]
            *(f16x8*)&xh[c0 * 72 + 16 * g + 8] = h1;
        }
        __syncthreads();   // all xf reads done before token residual writes

        // token G1: Htok[c][j] = gelu(xhT @ W1 + b1)
        {
            const f16x8 a0 = *(const f16x8*)&xh[(16 * w + r) * 72 + 8 * g];
            const f16x8 a1 = *(const f16x8*)&xh[(16 * w + r) * 72 + 32 + 8 * g];
            const _Float16* W1 = pT1 + l * 32 * 64;   // [j][k]
#pragma unroll
            for (int nt = 0; nt < 2; ++nt) {
                const int j = 16 * nt + r;
                const float bias = tok_b1[l * 32 + j];
                f32x4 acc = {bias, bias, bias, bias};
                const f16x8 b0 = *(const f16x8*)&W1[j * 64 + 8 * g];
                const f16x8 b1 = *(const f16x8*)&W1[j * 64 + 32 + 8 * g];
                acc = __builtin_amdgcn_mfma_f32_16x16x32_f16(a0, b0, acc, 0, 0, 0);
                acc = __builtin_amdgcn_mfma_f32_16x16x32_f16(a1, b1, acc, 0, 0, 0);
#pragma unroll
                for (int jj = 0; jj < 4; ++jj)
                    Hq[(16 * w + 4 * g + jj) * 36 + j] = gelu_f(acc[jj]);   // wave-local
            }
        }
        // token G2 (+ residual into xf, transposed)
        {
            f16x8 a2;
#pragma unroll
            for (int i = 0; i < 8; ++i)
                a2[i] = (_Float16)Hq[(16 * w + r) * 36 + 8 * g + i];
            const _Float16* W2 = pT2 + l * 64 * 32;   // [k][j]
#pragma unroll
            for (int nt = 0; nt < 4; ++nt) {
                const int kcol = 16 * nt + r;
                const float bias = tok_b2[l * 64 + kcol];
                f32x4 acc = {bias, bias, bias, bias};
                const f16x8 bf = *(const f16x8*)&W2[kcol * 32 + 8 * g];
                acc = __builtin_amdgcn_mfma_f32_16x16x32_f16(a2, bf, acc, 0, 0, 0);
#pragma unroll
                for (int jj = 0; jj < 4; ++jj)
                    xf[kcol * 68 + 16 * w + 4 * g + jj] += acc[jj];
            }
        }
        __syncthreads();   // residual complete before channel LN reads xf

        // ======== channel mixing: LN over c per k ========
        {
            const int k0 = 16 * w + r;
            float cv[16];
            float s = 0.f, ss = 0.f;
            const float* xrow = &xf[k0 * 68 + 16 * g];
#pragma unroll
            for (int u = 0; u < 16; ++u) {
                const float v = xrow[u];
                cv[u] = v; s += v; ss += v * v;
            }
            s += __shfl_xor(s, 16); ss += __shfl_xor(ss, 16);
            s += __shfl_xor(s, 32); ss += __shfl_xor(ss, 32);
            const float mean = s * (1.f / 64.f);
            const float rstd = rsqrtf(ss * (1.f / 64.f) - mean * mean + 1e-5f);
            const float* cls = ch_ln_s + l * 64 + 16 * g;
            const float* clb = ch_ln_b + l * 64 + 16 * g;
            f16x8 h0, h1;
#pragma unroll
            for (int u = 0; u < 8; ++u)
                h0[u] = (_Float16)((cv[u] - mean) * rstd * cls[u] + clb[u]);
#pragma unroll
            for (int u = 0; u < 8; ++u)
                h1[u] = (_Float16)((cv[8 + u] - mean) * rstd * cls[8 + u] + clb[8 + u]);
            *(f16x8*)&xh[k0 * 72 + 16 * g]     = h0;   // xh[k][c]
            *(f16x8*)&xh[k0 * 72 + 16 * g + 8] = h1;
        }
        __syncthreads();   // all xf reads done before channel residual writes

        // channel MLP in 4 n-quarters of 64; H quarter lives in Hq (wave-local)
        {
            const f16x8 ca0 = *(const f16x8*)&xh[(16 * w + r) * 72 + 8 * g];
            const f16x8 ca1 = *(const f16x8*)&xh[(16 * w + r) * 72 + 32 + 8 * g];
            f32x4 cacc[4];
#pragma unroll
            for (int nt = 0; nt < 4; ++nt) {
                const float bias = ch_b2[l * 64 + 16 * nt + r];
                cacc[nt] = {bias, bias, bias, bias};
            }
            const _Float16* Wc1 = pC1 + l * 256 * 64;   // [n][c]
            const _Float16* Wc2 = pC2 + l * 64 * 256;   // [c][n]
            for (int q = 0; q < 4; ++q) {
#pragma unroll
                for (int nt = 0; nt < 4; ++nt) {
                    const int n = 64 * q + 16 * nt + r;
                    const float bias = ch_b1[l * 256 + n];
                    f32x4 acc = {bias, bias, bias, bias};
                    const f16x8 b0 = *(const f16x8*)&Wc1[n * 64 + 8 * g];
                    const f16x8 b1 = *(const f16x8*)&Wc1[n * 64 + 32 + 8 * g];
                    acc = __builtin_amdgcn_mfma_f32_16x16x32_f16(ca0, b0, acc, 0, 0, 0);
                    acc = __builtin_amdgcn_mfma_f32_16x16x32_f16(ca1, b1, acc, 0, 0, 0);
#pragma unroll
                    for (int jj = 0; jj < 4; ++jj)
                        Hq[(16 * w + 4 * g + jj) * 68 + 16 * nt + r] = gelu_f(acc[jj]);
                }
#pragma unroll
                for (int ks = 0; ks < 2; ++ks) {
                    f16x8 a;
#pragma unroll
                    for (int i = 0; i < 8; ++i)
                        a[i] = (_Float16)Hq[(16 * w + r) * 68 + 32 * ks + 8 * g + i];
#pragma unroll
                    for (int nt = 0; nt < 4; ++nt) {
                        const f16x8 bf = *(const f16x8*)&Wc2[(16 * nt + r) * 256 + 64 * q + 32 * ks + 8 * g];
                        cacc[nt] = __builtin_amdgcn_mfma_f32_16x16x32_f16(a, bf, cacc[nt], 0, 0, 0);
                    }
                }
            }
#pragma unroll
            for (int nt = 0; nt < 4; ++nt)
#pragma unroll
                for (int jj = 0; jj < 4; ++jj)
                    xf[(16 * w + 4 * g + jj) * 68 + 16 * nt + r] += cacc[nt][jj];
        }
        __syncthreads();
    }

    // agg[b][c] = mean over k
    {
        float ssum = 0.f;
#pragma unroll
        for (int u = 0; u < 16; ++u) ssum += xf[(16 * g + u) * 68 + 16 * w + r];
        ssum += __shfl_xor(ssum, 16);
        ssum += __shfl_xor(ssum, 32);
        if (g == 0) agg_out[(size_t)b * 64 + 16 * w + r] = ssum * (1.f / 64.f);
    }
}

// ---------------------------------------------------------------------------
// Kernel 3: gap aggregation + output GEMV
// ---------------------------------------------------------------------------
__global__ __launch_bounds__(192)
void out_kernel(const float* __restrict__ node_table,
                const float* __restrict__ agg,
                const float* __restrict__ out_W,
                const float* __restrict__ out_b,
                const int*   __restrict__ node_ids,
                const int*   __restrict__ gap_ids,
                float* __restrict__ out) {
    __shared__ float inb[CAT_];
    const int b = blockIdx.x;
    const int t = threadIdx.x;

    if (t < 64) inb[t] = agg[(size_t)b * C_ + t];

    if (t < FEAT_) {
        const int* gid = gap_ids + (size_t)b * G_;
        float acc = 0.f;
        int nv = 0;
#pragma unroll 4
        for (int g = 0; g < G_; ++g) {
            const int id = gid[g];
            if (id > 0) { ++nv; acc += node_table[(size_t)id * FEAT_ + t]; }
        }
        const int nvs = (nv > 0) ? nv : 1;
        const float scale = 1.0f / (float)(G_ * nvs);
        const int nid = node_ids[b];
        inb[64 + t] = acc * scale + node_table[(size_t)nid * FEAT_ + t];
    }
    __syncthreads();

    if (t < FEAT_) {
        float o = out_b[t];
#pragma unroll 4
        for (int i = 0; i < CAT_; ++i) o += inb[i] * out_W[i * FEAT_ + t];
        out[(size_t)b * FEAT_ + t] = o;
    }
}

// ---------------------------------------------------------------------------
extern "C" void kernel_launch(void* const* d_in, const int* in_sizes, int n_in,
                              void* d_out, int out_size, void* d_ws, size_t ws_size,
                              hipStream_t stream) {
    const float* node_table = (const float*)d_in[0];
    const float* edge_table = (const float*)d_in[1];
    const float* time_w     = (const float*)d_in[2];
    const float* proj_W     = (const float*)d_in[3];
    const float* proj_b     = (const float*)d_in[4];
    const float* tok_ln_s   = (const float*)d_in[5];
    const float* tok_ln_b   = (const float*)d_in[6];
    const float* tok_W1     = (const float*)d_in[7];
    const float* tok_b1     = (const float*)d_in[8];
    const float* tok_W2     = (const float*)d_in[9];
    const float* tok_b2     = (const float*)d_in[10];
    const float* ch_ln_s    = (const float*)d_in[11];
    const float* ch_ln_b    = (const float*)d_in[12];
    const float* ch_W1      = (const float*)d_in[13];
    const float* ch_b1      = (const float*)d_in[14];
    const float* ch_W2      = (const float*)d_in[15];
    const float* ch_b2      = (const float*)d_in[16];
    const float* out_W      = (const float*)d_in[17];
    const float* out_b      = (const float*)d_in[18];
    const int*   node_ids   = (const int*)d_in[19];
    const int*   nbr_nids   = (const int*)d_in[20];
    const int*   nbr_eids   = (const int*)d_in[21];
    const int*   gap_ids    = (const int*)d_in[22];
    const float* node_times = (const float*)d_in[23];
    const float* nbr_times  = (const float*)d_in[24];

    float* x_buf   = (float*)d_ws;                       // B*K*C f32 = 128 MiB
    float* agg_buf = x_buf + (size_t)B_ * C_ * K_;       // B*C f32  = 2 MiB
    _Float16* pw   = (_Float16*)(agg_buf + (size_t)B_ * C_);
    _Float16* pT1  = pw;              // 2*32*64
    _Float16* pT2  = pw + 4096;       // 2*64*32
    _Float16* pC1  = pw + 8192;       // 2*256*64
    _Float16* pC2  = pw + 40960;      // 2*64*256
    float* outp    = (float*)d_out;

    prepack_kernel<<<64, 256, 0, stream>>>(tok_W1, tok_W2, ch_W1, ch_W2,
                                           pT1, pT2, pC1, pC2);
    proj_kernel<<<B_, 256, 0, stream>>>(edge_table, time_w, proj_W, proj_b,
                                        nbr_nids, nbr_eids, node_times, nbr_times,
                                        x_buf);
    mixer_mfma<<<B_, 256, 0, stream>>>(x_buf,
                                       tok_ln_s, tok_ln_b, tok_b1, tok_b2,
                                       ch_ln_s, ch_ln_b, ch_b1, ch_b2,
                                       pT1, pT2, pC1, pC2,
                                       agg_buf);
    out_kernel<<<B_, 192, 0, stream>>>(node_table, agg_buf, out_W, out_b,
                                       node_ids, gap_ids, outp);
}

// Round 4
// 955.773 us; speedup vs baseline: 1.9173x; 1.1640x over previous
//
#include <hip/hip_runtime.h>
#include <math.h>

#define B_    8192
#define K_    64
#define C_    64
#define FEAT_ 172
#define TDIM_ 100
#define TOKH_ 32
#define CHH_  256
#define G_    100
#define L_    2
#define CAT_  236      // C_+FEAT_

typedef _Float16 f16x8 __attribute__((ext_vector_type(8)));
typedef _Float16 f16x4 __attribute__((ext_vector_type(4)));
typedef float    f32x4 __attribute__((ext_vector_type(4)));

__device__ __forceinline__ float gelu_f(float x) {
    // exact-form GELU via Abramowitz-Stegun 7.1.26 erf (|err| < 1.5e-7)
    const float z  = x * 0.70710678118654752f;
    const float az = fabsf(z);
    const float t  = 1.0f / (1.0f + 0.3275911f * az);
    const float poly = t * (0.254829592f + t * (-0.284496736f + t * (1.421413741f
                     + t * (-1.453152027f + t * 1.061405429f))));
    const float e  = __expf(-az * az);
    float erfv = 1.0f - poly * e;
    erfv = copysignf(erfv, z);
    return 0.5f * x * (1.0f + erfv);
}

// ---------------------------------------------------------------------------
// Prepack weights to f16, layouts chosen so every MFMA A/B fragment is one
// contiguous 16B load.
// ---------------------------------------------------------------------------
__global__ __launch_bounds__(256)
void prepack_kernel(const float* __restrict__ proj_W,
                    const float* __restrict__ tW1, const float* __restrict__ tW2,
                    const float* __restrict__ cW1, const float* __restrict__ cW2,
                    _Float16* __restrict__ pW,
                    _Float16* __restrict__ pT1, _Float16* __restrict__ pT2,
                    _Float16* __restrict__ pC1, _Float16* __restrict__ pC2) {
    const int stride = gridDim.x * blockDim.x;
    const int t0 = blockIdx.x * blockDim.x + threadIdx.x;
    // pW[c][i] (64 x 288): = proj_W[i][c], zero-pad i>=272
    for (int i = t0; i < 64 * 288; i += stride) {
        const int c = i / 288, ii = i % 288;
        pW[i] = (ii < 272) ? (_Float16)proj_W[ii * 64 + c] : (_Float16)0.f;
    }
    // pT1[l][j][k] = tW1[l][k][j]   tW1: (2,64,32)
    for (int i = t0; i < 2 * 32 * 64; i += stride) {
        const int l = i / 2048, rem = i % 2048, j = rem / 64, k = rem % 64;
        pT1[i] = (_Float16)tW1[l * 2048 + k * 32 + j];
    }
    // pT2[l][k][j] = tW2[l][j][k]   tW2: (2,32,64)
    for (int i = t0; i < 2 * 64 * 32; i += stride) {
        const int l = i / 2048, rem = i % 2048, k = rem / 32, j = rem % 32;
        pT2[i] = (_Float16)tW2[l * 2048 + j * 64 + k];
    }
    // pC1[l][n][c] = cW1[l][c][n]   cW1: (2,64,256)
    for (int i = t0; i < 2 * 256 * 64; i += stride) {
        const int l = i / 16384, rem = i % 16384, n = rem / 64, c = rem % 64;
        pC1[i] = (_Float16)cW1[l * 16384 + c * 256 + n];
    }
    // pC2[l][c][n] = cW2[l][n][c]   cW2: (2,256,64)
    for (int i = t0; i < 2 * 64 * 256; i += stride) {
        const int l = i / 16384, rem = i % 16384, c = rem / 256, n = rem % 256;
        pC2[i] = (_Float16)cW2[l * 16384 + n * 64 + c];
    }
}

// ---------------------------------------------------------------------------
// Fused: gather+time-encode+proj (MFMA, K=288) -> 2 mixer layers -> agg.
// One b per block, 4 waves, wave w owns k-rows / c-slice [16w,16w+16).
// All GEMMs use swapped operands mfma(W_frag, act_frag) so D-fragments are
// address-contiguous: vector H writes (f16x4), vector residual RMW (f32x4,
// bank-even), vector bias loads. Only 2 barriers per layer.
// Frag maps (HW-verified rounds 1-2): A/B: lane l -> row/col l&15,
// K-elem 8*(l>>4)+i ; D: col l&15, row 4*(l>>4)+jj.
// FIX vs round 3: chunk B is restaged at column 0 of each stride-168 row
// (cols 0..127). The previous "+160" LDS offset overran the row stride
// (row k spilled into row k+1; row 63 wrote 240 B past the Ubuf end -> OOB
// LDS -> NaN). The +160 remains only on the pW global side where the row
// really is 288 wide.
// ---------------------------------------------------------------------------
__global__ __launch_bounds__(256, 4)
void fused_kernel(const float* __restrict__ edge_table,
                  const float* __restrict__ time_w,
                  const _Float16* __restrict__ pW,
                  const float* __restrict__ proj_b,
                  const int*   __restrict__ nbr_nids,
                  const int*   __restrict__ nbr_eids,
                  const float* __restrict__ node_times,
                  const float* __restrict__ nbr_times,
                  const float* __restrict__ tok_ln_s, const float* __restrict__ tok_ln_b,
                  const float* __restrict__ tok_b1,   const float* __restrict__ tok_b2,
                  const float* __restrict__ ch_ln_s,  const float* __restrict__ ch_ln_b,
                  const float* __restrict__ ch_b1,    const float* __restrict__ ch_b2,
                  const _Float16* __restrict__ pT1, const _Float16* __restrict__ pT2,
                  const _Float16* __restrict__ pC1, const _Float16* __restrict__ pC2,
                  float* __restrict__ agg_out) {
    __shared__ __attribute__((aligned(16))) float xf[64 * 68];      // 17408 B
    __shared__ __attribute__((aligned(16))) char  Ubuf[64 * 168 * 2]; // 21504 B
    _Float16* inT = (_Float16*)Ubuf;            // proj staging [64][168]
    _Float16* xh  = (_Float16*)Ubuf;            // LN out [64][72] (9216 B)
    _Float16* hb  = (_Float16*)(Ubuf + 9216);   // token [64][40] / channel [64][72]

    const int b    = blockIdx.x;
    const int t    = threadIdx.x;
    const int lane = t & 63;
    const int w    = t >> 6;
    const int r    = lane & 15;
    const int g    = lane >> 4;
    const int row16 = 16 * w + r;

    // ================= proj phase =================
    const int kq = t >> 2;          // row 0..63
    const int q4 = t & 3;
    const size_t eid = (size_t)nbr_eids[b * K_ + kq];
    const float* erow = edge_table + eid * FEAT_;
    const int   nz = (nbr_nids[b * K_ + kq] == 0);
    const float dt = node_times[b] - nbr_times[b * K_ + kq];

    // stage chunk A: i = 0..159 (edge cols), row-local cols 0..159
    {
        _Float16* dst = inT + kq * 168;
#pragma unroll
        for (int j = 0; j < 10; ++j) {
            const float4 v = *(const float4*)(erow + 40 * q4 + 4 * j);
            f16x4 h = {(_Float16)v.x, (_Float16)v.y, (_Float16)v.z, (_Float16)v.w};
            *(f16x4*)&dst[40 * q4 + 4 * j] = h;
        }
    }
    __syncthreads();

    f32x4 pacc[4];
#pragma unroll
    for (int nt = 0; nt < 4; ++nt)
        pacc[nt] = *(const f32x4*)&proj_b[16 * nt + 4 * g];

#pragma unroll
    for (int kk = 0; kk < 5; ++kk) {
        const f16x8 bfrag = *(const f16x8*)&inT[row16 * 168 + 32 * kk + 8 * g];
#pragma unroll
        for (int nt = 0; nt < 4; ++nt) {
            const f16x8 afrag = *(const f16x8*)&pW[(16 * nt + r) * 288 + 32 * kk + 8 * g];
            pacc[nt] = __builtin_amdgcn_mfma_f32_16x16x32_f16(afrag, bfrag, pacc[nt], 0, 0, 0);
        }
    }
    __syncthreads();   // all reads of chunk A done before restage

    // stage chunk B: global i = 160..287 -> row-local cols 0..127
    // (local col 0..11 = edge 160..171; 12..111 = time 0..99; 112..127 = pad)
    {
        _Float16* dst = inT + kq * 168;
        if (q4 == 0) {
#pragma unroll
            for (int j = 0; j < 3; ++j) {
                const float4 v = *(const float4*)(erow + 160 + 4 * j);
                f16x4 h = {(_Float16)v.x, (_Float16)v.y, (_Float16)v.z, (_Float16)v.w};
                *(f16x4*)&dst[4 * j] = h;
            }
            for (int d = 0; d < 20; ++d)
                dst[12 + d] = nz ? (_Float16)0.f : (_Float16)cosf(dt * time_w[d]);
        } else if (q4 == 3) {
            for (int d = 84; d < 100; ++d)
                dst[12 + d] = nz ? (_Float16)0.f : (_Float16)cosf(dt * time_w[d]);
            for (int i2 = 112; i2 < 128; ++i2) dst[i2] = (_Float16)0.f;
        } else {
            for (int d = 32 * q4 - 12; d < 32 * q4 + 20; ++d)
                dst[12 + d] = nz ? (_Float16)0.f : (_Float16)cosf(dt * time_w[d]);
        }
    }
    __syncthreads();

#pragma unroll
    for (int kk = 0; kk < 4; ++kk) {
        const f16x8 bfrag = *(const f16x8*)&inT[row16 * 168 + 32 * kk + 8 * g];
#pragma unroll
        for (int nt = 0; nt < 4; ++nt) {
            const f16x8 afrag = *(const f16x8*)&pW[(16 * nt + r) * 288 + 160 + 32 * kk + 8 * g];
            pacc[nt] = __builtin_amdgcn_mfma_f32_16x16x32_f16(afrag, bfrag, pacc[nt], 0, 0, 0);
        }
    }
    // x[k][c]: lane: k = row16, c = 16nt+4g..+3
#pragma unroll
    for (int nt = 0; nt < 4; ++nt)
        *(f32x4*)&xf[row16 * 68 + 16 * nt + 4 * g] = pacc[nt];
    __syncthreads();

    // ================= mixer layers =================
    for (int l = 0; l < L_; ++l) {
        // ---- token LN (over k, per c); c-slice wave-local ----
        {
            const int c0 = row16;
            float xv[16], s = 0.f, ss = 0.f;
#pragma unroll
            for (int u = 0; u < 16; ++u) {
                const float v = xf[(16 * g + u) * 68 + c0];
                xv[u] = v; s += v; ss += v * v;
            }
            s += __shfl_xor(s, 16); ss += __shfl_xor(ss, 16);
            s += __shfl_xor(s, 32); ss += __shfl_xor(ss, 32);
            const float mean = s * 0.015625f;
            const float rstd = rsqrtf(ss * 0.015625f - mean * mean + 1e-5f);
            const float* tls = tok_ln_s + l * 64 + 16 * g;
            const float* tlb = tok_ln_b + l * 64 + 16 * g;
            f16x8 h0, h1;
#pragma unroll
            for (int u = 0; u < 8; ++u)
                h0[u] = (_Float16)((xv[u] - mean) * rstd * tls[u] + tlb[u]);
#pragma unroll
            for (int u = 0; u < 8; ++u)
                h1[u] = (_Float16)((xv[8 + u] - mean) * rstd * tls[8 + u] + tlb[8 + u]);
            *(f16x8*)&xh[c0 * 72 + 16 * g]     = h0;   // xh^T[c][k]
            *(f16x8*)&xh[c0 * 72 + 16 * g + 8] = h1;
        }
        // ---- token G1: Htok[c][j] = gelu(xh^T W1 + b1) ----
        {
            const f16x8 b0 = *(const f16x8*)&xh[row16 * 72 + 8 * g];
            const f16x8 b1 = *(const f16x8*)&xh[row16 * 72 + 32 + 8 * g];
            const _Float16* W1 = pT1 + l * 2048;   // [j][k]
#pragma unroll
            for (int nt = 0; nt < 2; ++nt) {
                f32x4 acc = *(const f32x4*)&tok_b1[l * 32 + 16 * nt + 4 * g];
                const f16x8 a0 = *(const f16x8*)&W1[(16 * nt + r) * 64 + 8 * g];
                const f16x8 a1 = *(const f16x8*)&W1[(16 * nt + r) * 64 + 32 + 8 * g];
                acc = __builtin_amdgcn_mfma_f32_16x16x32_f16(a0, b0, acc, 0, 0, 0);
                acc = __builtin_amdgcn_mfma_f32_16x16x32_f16(a1, b1, acc, 0, 0, 0);
                // D: j = 16nt+4g+jj, c = row16
                f16x4 hq;
#pragma unroll
                for (int jj = 0; jj < 4; ++jj) hq[jj] = (_Float16)gelu_f(acc[jj]);
                *(f16x4*)&hb[row16 * 40 + 16 * nt + 4 * g] = hq;
            }
        }
        // ---- token G2 + residual (c-slice wave-local) ----
        {
            const f16x8 a = *(const f16x8*)&hb[row16 * 40 + 8 * g];  // A: c=row16, j contig
            const _Float16* W2 = pT2 + l * 2048;   // [k][j]
#pragma unroll
            for (int nt = 0; nt < 4; ++nt) {
                const int kcol = 16 * nt + r;
                const float bk = tok_b2[l * 64 + kcol];
                f32x4 acc = {bk, bk, bk, bk};
                const f16x8 bf = *(const f16x8*)&W2[kcol * 32 + 8 * g];
                acc = __builtin_amdgcn_mfma_f32_16x16x32_f16(a, bf, acc, 0, 0, 0);
                // D: c = 16w+4g+jj, k = kcol
                float* p = &xf[kcol * 68 + 16 * w + 4 * g];
                const f32x4 old = *(const f32x4*)p;
                *(f32x4*)p = old + acc;
            }
        }
        __syncthreads();   // token residual visible to all before channel LN

        // ---- channel LN (over c, per k); k-row wave-local ----
        {
            const int k0 = row16;
            f32x4 cv[4];
            float s = 0.f, ss = 0.f;
#pragma unroll
            for (int uu = 0; uu < 4; ++uu) {
                cv[uu] = *(const f32x4*)&xf[k0 * 68 + 16 * g + 4 * uu];
#pragma unroll
                for (int e = 0; e < 4; ++e) { s += cv[uu][e]; ss += cv[uu][e] * cv[uu][e]; }
            }
            s += __shfl_xor(s, 16); ss += __shfl_xor(ss, 16);
            s += __shfl_xor(s, 32); ss += __shfl_xor(ss, 32);
            const float mean = s * 0.015625f;
            const float rstd = rsqrtf(ss * 0.015625f - mean * mean + 1e-5f);
            const float* cls = ch_ln_s + l * 64 + 16 * g;
            const float* clb = ch_ln_b + l * 64 + 16 * g;
            f16x8 h0, h1;
#pragma unroll
            for (int uu = 0; uu < 4; ++uu)
#pragma unroll
                for (int e = 0; e < 4; ++e) {
                    const float hv = (cv[uu][e] - mean) * rstd * cls[4 * uu + e] + clb[4 * uu + e];
                    if (uu < 2) h0[4 * uu + e] = (_Float16)hv;
                    else        h1[4 * (uu - 2) + e] = (_Float16)hv;
                }
            *(f16x8*)&xh[k0 * 72 + 16 * g]     = h0;   // xh[k][c]
            *(f16x8*)&xh[k0 * 72 + 16 * g + 8] = h1;
        }
        // ---- channel MLP (4 n-quarters; hb quarter wave-local, no barriers) ----
        {
            const f16x8 ca0 = *(const f16x8*)&xh[row16 * 72 + 8 * g];
            const f16x8 ca1 = *(const f16x8*)&xh[row16 * 72 + 32 + 8 * g];
            const _Float16* Wc1 = pC1 + l * 16384;   // [n][c]
            const _Float16* Wc2 = pC2 + l * 16384;   // [c][n]
            f32x4 cacc[4];
#pragma unroll
            for (int nt = 0; nt < 4; ++nt)
                cacc[nt] = *(const f32x4*)&ch_b2[l * 64 + 16 * nt + 4 * g];
            for (int q = 0; q < 4; ++q) {
#pragma unroll
                for (int nt = 0; nt < 4; ++nt) {
                    const int nrow = 64 * q + 16 * nt + r;
                    f32x4 acc = *(const f32x4*)&ch_b1[l * 256 + 64 * q + 16 * nt + 4 * g];
                    const f16x8 a0 = *(const f16x8*)&Wc1[nrow * 64 + 8 * g];
                    const f16x8 a1 = *(const f16x8*)&Wc1[nrow * 64 + 32 + 8 * g];
                    acc = __builtin_amdgcn_mfma_f32_16x16x32_f16(a0, ca0, acc, 0, 0, 0);
                    acc = __builtin_amdgcn_mfma_f32_16x16x32_f16(a1, ca1, acc, 0, 0, 0);
                    // D: n_local = 16nt+4g+jj, k = row16
                    f16x4 hq;
#pragma unroll
                    for (int jj = 0; jj < 4; ++jj) hq[jj] = (_Float16)gelu_f(acc[jj]);
                    *(f16x4*)&hb[row16 * 72 + 16 * nt + 4 * g] = hq;
                }
#pragma unroll
                for (int ks = 0; ks < 2; ++ks) {
                    const f16x8 bh = *(const f16x8*)&hb[row16 * 72 + 32 * ks + 8 * g];
#pragma unroll
                    for (int nt2 = 0; nt2 < 4; ++nt2) {
                        const f16x8 a2 = *(const f16x8*)&Wc2[(16 * nt2 + r) * 256 + 64 * q + 32 * ks + 8 * g];
                        cacc[nt2] = __builtin_amdgcn_mfma_f32_16x16x32_f16(a2, bh, cacc[nt2], 0, 0, 0);
                    }
                }
            }
            // residual: lane: k = row16, c = 16nt2+4g..+3
#pragma unroll
            for (int nt2 = 0; nt2 < 4; ++nt2) {
                float* p = &xf[row16 * 68 + 16 * nt2 + 4 * g];
                const f32x4 old = *(const f32x4*)p;
                *(f32x4*)p = old + cacc[nt2];
            }
        }
        __syncthreads();   // layer complete
    }

    // ---- agg: mean over k per c ----
    {
        float ssum = 0.f;
#pragma unroll
        for (int u = 0; u < 16; ++u) ssum += xf[(16 * g + u) * 68 + row16];
        ssum += __shfl_xor(ssum, 16);
        ssum += __shfl_xor(ssum, 32);
        if (g == 0) agg_out[(size_t)b * 64 + row16] = ssum * 0.015625f;
    }
}

// ---------------------------------------------------------------------------
// Kernel 3: gap aggregation + output GEMV
// ---------------------------------------------------------------------------
__global__ __launch_bounds__(192)
void out_kernel(const float* __restrict__ node_table,
                const float* __restrict__ agg,
                const float* __restrict__ out_W,
                const float* __restrict__ out_b,
                const int*   __restrict__ node_ids,
                const int*   __restrict__ gap_ids,
                float* __restrict__ out) {
    __shared__ float inb[CAT_];
    const int b = blockIdx.x;
    const int t = threadIdx.x;

    if (t < 64) inb[t] = agg[(size_t)b * C_ + t];

    if (t < FEAT_) {
        const int* gid = gap_ids + (size_t)b * G_;
        float acc = 0.f;
        int nv = 0;
#pragma unroll 4
        for (int g = 0; g < G_; ++g) {
            const int id = gid[g];
            if (id > 0) { ++nv; acc += node_table[(size_t)id * FEAT_ + t]; }
        }
        const int nvs = (nv > 0) ? nv : 1;
        const float scale = 1.0f / (float)(G_ * nvs);
        const int nid = node_ids[b];
        inb[64 + t] = acc * scale + node_table[(size_t)nid * FEAT_ + t];
    }
    __syncthreads();

    if (t < FEAT_) {
        float o = out_b[t];
#pragma unroll 4
        for (int i = 0; i < CAT_; ++i) o += inb[i] * out_W[i * FEAT_ + t];
        out[(size_t)b * FEAT_ + t] = o;
    }
}

// ---------------------------------------------------------------------------
extern "C" void kernel_launch(void* const* d_in, const int* in_sizes, int n_in,
                              void* d_out, int out_size, void* d_ws, size_t ws_size,
                              hipStream_t stream) {
    const float* node_table = (const float*)d_in[0];
    const float* edge_table = (const float*)d_in[1];
    const float* time_w     = (const float*)d_in[2];
    const float* proj_W     = (const float*)d_in[3];
    const float* proj_b     = (const float*)d_in[4];
    const float* tok_ln_s   = (const float*)d_in[5];
    const float* tok_ln_b   = (const float*)d_in[6];
    const float* tok_W1     = (const float*)d_in[7];
    const float* tok_b1     = (const float*)d_in[8];
    const float* tok_W2     = (const float*)d_in[9];
    const float* tok_b2     = (const float*)d_in[10];
    const float* ch_ln_s    = (const float*)d_in[11];
    const float* ch_ln_b    = (const float*)d_in[12];
    const float* ch_W1      = (const float*)d_in[13];
    const float* ch_b1      = (const float*)d_in[14];
    const float* ch_W2      = (const float*)d_in[15];
    const float* ch_b2      = (const float*)d_in[16];
    const float* out_W      = (const float*)d_in[17];
    const float* out_b      = (const float*)d_in[18];
    const int*   node_ids   = (const int*)d_in[19];
    const int*   nbr_nids   = (const int*)d_in[20];
    const int*   nbr_eids   = (const int*)d_in[21];
    const int*   gap_ids    = (const int*)d_in[22];
    const float* node_times = (const float*)d_in[23];
    const float* nbr_times  = (const float*)d_in[24];

    float* agg_buf = (float*)d_ws;                       // B*C f32 = 2 MiB
    _Float16* pw   = (_Float16*)(agg_buf + (size_t)B_ * C_);
    _Float16* pW   = pw;               // 64*288   = 18432
    _Float16* pT1  = pW  + 18432;      // 2*32*64  = 4096
    _Float16* pT2  = pT1 + 4096;       // 2*64*32  = 4096
    _Float16* pC1  = pT2 + 4096;       // 2*256*64 = 32768
    _Float16* pC2  = pC1 + 32768;      // 2*64*256 = 32768
    float* outp    = (float*)d_out;

    prepack_kernel<<<64, 256, 0, stream>>>(proj_W, tok_W1, tok_W2, ch_W1, ch_W2,
                                           pW, pT1, pT2, pC1, pC2);
    fused_kernel<<<B_, 256, 0, stream>>>(edge_table, time_w, pW, proj_b,
                                         nbr_nids, nbr_eids, node_times, nbr_times,
                                         tok_ln_s, tok_ln_b, tok_b1, tok_b2,
                                         ch_ln_s, ch_ln_b, ch_b1, ch_b2,
                                         pT1, pT2, pC1, pC2,
                                         agg_buf);
    out_kernel<<<B_, 192, 0, stream>>>(node_table, agg_buf, out_W, out_b,
                                       node_ids, gap_ids, outp);
}